// Round 13
// baseline (233.074 us; speedup 1.0000x reference)
//
#include <hip/hip_runtime.h>
#include <stdint.h>

#define NSEL 300
#define BB 2
#define QQ 900
#define CC 91
#define NQC (QQ * CC)   // 81900
#define MH 128
#define MW 128
#define TGT 512

#define NBUCKET 4096
#define CAND_CAP 4096

typedef float floatx4 __attribute__((ext_vector_type(4)));

// ---- d_ws byte offsets ----
#define WS_KEYS   0               // u32 [2][81900]  (655200 B, pad to 655360)
#define WS_SEL    655360          // int [600]

// -------- K1: FUSED top-k: sigmoid+hist | scan->cut | collect | rank --------
// One block per batch, 1024 threads. Histogram in LDS end-to-end (no global
// partials round-trip, no second launch). Key/tie/FP semantics identical to
// the R10 hist+select pair.
__global__ __launch_bounds__(1024) void topk_fused_kernel(
    const float* __restrict__ logits,    // [B,Q,C]
    const float* __restrict__ boxes_in,  // [B,Q,4]
    const float* __restrict__ logvars,   // [B,Q,4]
    const int*   __restrict__ tsizes,    // [B,2]
    float* __restrict__ out,
    uint8_t* __restrict__ ws)
{
    __shared__ uint32_t hist[NBUCKET];               // 16 KB
    __shared__ unsigned long long cand[CAND_CAP];    // 32 KB
    __shared__ uint32_t wsum[16];
    __shared__ int s_count;
    __shared__ int s_cut;

    const int b    = blockIdx.x;
    const int tid  = threadIdx.x;
    const int lane = tid & 63;
    const int wid  = tid >> 6;

    uint32_t* keys = (uint32_t*)(ws + WS_KEYS) + (size_t)b * NQC;

    for (int i = tid; i < NBUCKET; i += 1024) hist[i] = 0u;
    if (tid == 0) s_count = 0;
    __syncthreads();

    // ---- Phase 1: sigmoid -> key -> store + LDS histogram ----
    const float* lg = logits + (size_t)b * NQC;
    for (int i = tid; i < NQC; i += 1024) {
        float x = lg[i];
        float p = 1.0f / (1.0f + expf(-x));      // identical expression
        uint32_t key = __float_as_uint(p);
        keys[i] = key;
        atomicAdd(&hist[key >> 18], 1u);
    }
    __syncthreads();

    // ---- Phase 2: register suffix scan over buckets (thread owns 4) ----
    {
        const uint32_t h0 = hist[4 * tid];
        const uint32_t h1 = hist[4 * tid + 1];
        const uint32_t h2 = hist[4 * tid + 2];
        const uint32_t h3 = hist[4 * tid + 3];
        const uint32_t val = h0 + h1 + h2 + h3;

        uint32_t acc = val;
        #pragma unroll
        for (int off = 1; off < 64; off <<= 1) {
            uint32_t o = __shfl_down(acc, off, 64);
            if (lane + off < 64) acc += o;
        }
        if (lane == 0) wsum[wid] = acc;
        __syncthreads();

        uint32_t later = 0;
        for (int w = wid + 1; w < 16; ++w) later += wsum[w];
        const uint32_t sfx      = acc + later;
        const uint32_t sfx_next = sfx - val;

        if (sfx >= NSEL && sfx_next < NSEL) {
            int a = (int)sfx_next;
            int cut = 4 * tid;
            const uint32_t hh[4] = { h0, h1, h2, h3 };
            for (int k = 3; k >= 0; --k) {
                a += (int)hh[k];
                if (a >= NSEL) { cut = 4 * tid + k; break; }
            }
            s_cut = cut;
        }
    }
    __syncthreads();
    const uint32_t cut = (uint32_t)s_cut;

    // ---- Phase 3: collect candidates >= cut (keys are L2-hot) ----
    for (int i = tid; i < NQC; i += 1024) {
        uint32_t key = keys[i];
        if ((key >> 18) >= cut) {
            int pos = atomicAdd(&s_count, 1);
            if (pos < CAND_CAP) {
                cand[pos] = ((unsigned long long)key << 32)
                          | (uint32_t)(~(uint32_t)i);
            }
        }
    }
    __syncthreads();

    int count = s_count;
    if (count > CAND_CAP) count = CAND_CAP;

    // ---- Phase 4: rank-select + epilogue ----
    float* out_scores = out;                 // [B*NSEL]
    float* out_labels = out + 600;
    float* out_boxes  = out + 1200;
    float* out_unc    = out + 3600;
    int*   sel        = (int*)(ws + WS_SEL);

    for (int i = tid; i < count; i += 1024) {
        const unsigned long long my = cand[i];
        int r = 0;
        for (int j = 0; j < count; ++j) r += (cand[j] > my) ? 1 : 0;
        if (r < NSEL) {
            const uint32_t key = (uint32_t)(my >> 32);
            const uint32_t idx = ~((uint32_t)(my & 0xFFFFFFFFull));
            const int q = (int)(idx / CC);
            const int label = (int)(idx - (uint32_t)q * CC);
            const int o = b * NSEL + r;

            out_scores[o] = __uint_as_float(key);
            out_labels[o] = (float)label;

            const float* bx = boxes_in + ((size_t)(b * QQ + q)) * 4;
            float cx = bx[0], cy = bx[1], w = bx[2], hgt = bx[3];
            float hh2 = (float)tsizes[b * 2 + 0];
            float ww2 = (float)tsizes[b * 2 + 1];
            out_boxes[o * 4 + 0] = (cx - 0.5f * w) * ww2;
            out_boxes[o * 4 + 1] = (cy - 0.5f * hgt) * hh2;
            out_boxes[o * 4 + 2] = (cx + 0.5f * w) * ww2;
            out_boxes[o * 4 + 3] = (cy + 0.5f * hgt) * hh2;

            const float* gv = logvars + ((size_t)(b * QQ + q)) * 4;
            float s0 = gv[0] + gv[1];
            float s1 = s0 + gv[2];
            float s2 = s1 + gv[3];
            out_unc[o] = s2 * 0.25f;

            sel[o] = q;
        }
    }
}

// ---------------- K2: bilinear upsample 128->512 + threshold ----------
// Byte-identical to R10 (best mask config: 1600 blocks x 3 items,
// register-cached blends + burst nt-stores).
__global__ __launch_bounds__(256) void mask_kernel(
    const float* __restrict__ masks_in,  // [B,Q,128,128]
    const int*   __restrict__ sel,       // [B*NSEL]
    float* __restrict__ out_masks)       // [B*NSEL,512,512]
{
    __shared__ float S[18 * MW];         // 9216 B

    const int xg = threadIdx.x & 127;    // output cols 4xg..4xg+3
    const int rh = threadIdx.x >> 7;     // row half (0/1) within 64-row item
    const int cm1 = (xg == 0)   ? 0   : xg - 1;
    const int cp1 = (xg == 127) ? 127 : xg + 1;
    const bool eL = (xg == 0);
    const bool eR = (xg == 127);

    const int it0 = 3 * blockIdx.x;      // exactly 3 items per block
    for (int item = it0; item < it0 + 3; ++item) {
        const int m = item >> 3;         // 0..599
        const int e = item & 7;          // eighth: 64 rows
        const int b = m / NSEL;
        const int q = sel[m];

        const float* src = masks_in + ((size_t)(b * QQ + q)) * (MH * MW);
        float* dst = out_masks + (size_t)m * (TGT * TGT);

        const int y0   = e * 64;
        const int r_lo = (e == 0) ? 0   : (16 * e - 1);
        const int r_hi = (e == 7) ? 127 : (16 * e + 16);
        const int nrows = r_hi - r_lo + 1;   // 17 or 18

        {
            const float4* s4 = (const float4*)(src + (size_t)r_lo * MW);
            float4* d4 = (float4*)S;
            const int n4 = nrows * (MW / 4);
            for (int i = threadIdx.x; i < n4; i += 256) d4[i] = s4[i];
        }
        __syncthreads();

        // ---- Phase 1: horizontal blends for input rows k0-1 .. k0+8 ----
        const int k0    = 16 * e + 8 * rh;   // first out-row group index
        const int rbase = k0 - 1;
        floatx4 h[10];
        #pragma unroll
        for (int j = 0; j < 10; ++j) {
            int r = rbase + j;
            r = (r < 0) ? 0 : (r > MH - 1 ? MH - 1 : r);
            const float* R = S + (r - r_lo) * MW;
            const float a = R[cm1];
            const float c = R[xg];
            const float p = R[cp1];
            floatx4 v;
            v.x = eL ? c : fmaf(0.375f, a, 0.625f * c);
            v.y = eL ? c : fmaf(0.125f, a, 0.875f * c);
            v.z = eR ? c : fmaf(0.125f, p, 0.875f * c);
            v.w = eR ? c : fmaf(0.375f, p, 0.625f * c);
            h[j] = v;
        }

        // ---- Phase 2: vertical lerps + burst stores ----
        float* dhalf = dst + (size_t)(y0 + rh * 32) * TGT + 4 * xg;
        #pragma unroll
        for (int g = 0; g < 8; ++g) {
            const floatx4 hA = h[g];
            const floatx4 hB = h[g + 1];
            const floatx4 hC = h[g + 2];
            const floatx4 dAB = hB - hA;
            const floatx4 dBC = hC - hB;

            floatx4 vA, vB, vC, vD;
            #pragma unroll
            for (int u = 0; u < 4; ++u) {
                vA[u] = fmaf(0.625f, dAB[u], hA[u]);
                vB[u] = fmaf(0.875f, dAB[u], hA[u]);
                vC[u] = fmaf(0.125f, dBC[u], hB[u]);
                vD[u] = fmaf(0.375f, dBC[u], hB[u]);
            }
            floatx4 rA, rB, rC, rD;
            #pragma unroll
            for (int u = 0; u < 4; ++u) {
                rA[u] = (vA[u] > 0.0f) ? 1.0f : 0.0f;
                rB[u] = (vB[u] > 0.0f) ? 1.0f : 0.0f;
                rC[u] = (vC[u] > 0.0f) ? 1.0f : 0.0f;
                rD[u] = (vD[u] > 0.0f) ? 1.0f : 0.0f;
            }
            floatx4* p0 = (floatx4*)(dhalf + (size_t)(4 * g    ) * TGT);
            floatx4* p1 = (floatx4*)(dhalf + (size_t)(4 * g + 1) * TGT);
            floatx4* p2 = (floatx4*)(dhalf + (size_t)(4 * g + 2) * TGT);
            floatx4* p3 = (floatx4*)(dhalf + (size_t)(4 * g + 3) * TGT);
            __builtin_nontemporal_store(rA, p0);
            __builtin_nontemporal_store(rB, p1);
            __builtin_nontemporal_store(rC, p2);
            __builtin_nontemporal_store(rD, p3);
        }
        __syncthreads();   // LDS reuse guard before next item's stage
    }
}

extern "C" void kernel_launch(void* const* d_in, const int* in_sizes, int n_in,
                              void* d_out, int out_size, void* d_ws, size_t ws_size,
                              hipStream_t stream) {
    (void)in_sizes; (void)n_in; (void)out_size; (void)ws_size;

    const float* pred_logits  = (const float*)d_in[0];  // [2,900,91]
    const float* pred_boxes   = (const float*)d_in[1];  // [2,900,4]
    const float* pred_masks   = (const float*)d_in[2];  // [2,900,128,128]
    const float* pred_logvars = (const float*)d_in[3];  // [2,900,4]
    const int*   target_sizes = (const int*)d_in[4];    // [2,2]

    float*   out = (float*)d_out;
    uint8_t* ws  = (uint8_t*)d_ws;

    hipLaunchKernelGGL(topk_fused_kernel, dim3(BB), dim3(1024), 0, stream,
                       pred_logits, pred_boxes, pred_logvars, target_sizes,
                       out, ws);

    float* out_masks = out + 4200;
    const int* sel = (const int*)(ws + WS_SEL);
    hipLaunchKernelGGL(mask_kernel, dim3(1600), dim3(256), 0, stream,
                       pred_masks, sel, out_masks);
}